// Round 8
// baseline (73.680 us; speedup 1.0000x reference)
//
#include <hip/hip_runtime.h>

#define BB 16
#define CC 64
#define DD 16
#define HW 2304     // 48*48
#define HID 16
#define NEG_SLOPE 0.01f
#define CH4 9216    // float4 stride between channels at fixed (b,d)
#define NSLICE 256  // B*D slices
#define NBLK 512    // 2 half-slice blocks per slice

using f4 = __attribute__((ext_vector_type(4))) float;

// Pack 4 fp32 -> 4 bf16 (two dwords). Single-inst asm, no early-clobber needed.
__device__ __forceinline__ uint2 pack_bf16x4(f4 v) {
    uint2 r;
    asm("v_cvt_pk_bf16_f32 %0, %1, %2" : "=v"(r.x) : "v"(v.x), "v"(v.y));
    asm("v_cvt_pk_bf16_f32 %0, %1, %2" : "=v"(r.y) : "v"(v.z), "v"(v.w));
    return r;
}

__device__ __forceinline__ f4 unpack_mul(uint2 p, float g) {
    f4 v;
    v.x = __uint_as_float(p.x << 16) * g;
    v.y = __uint_as_float(p.x & 0xffff0000u) * g;
    v.z = __uint_as_float(p.y << 16) * g;
    v.w = __uint_as_float(p.y & 0xffff0000u) * g;
    return v;
}

// Reset per-slice handshake counters (ws is 0xAA-poisoned / stale across calls).
__global__ void zero_flags_kernel(unsigned* __restrict__ flags) {
    if (threadIdx.x < NSLICE) flags[threadIdx.x] = 0u;
}

// 512 blocks x 1024 threads: block g handles channels [32*(g&1), +32) of slice
// g>>1. Per wave: 2 channels x 9 float4, ALL retained in registers as bf16
// (36 data VGPRs). LDS < 1 KB -> 2 blocks/CU -> 32 waves/CU (vs R7's 16).
// Sibling half-blocks exchange pooled values via ws with agent-scope atomics.
// __launch_bounds__(1024, 8) hard-caps VGPR at 64 => all 512 blocks
// co-resident (512*16 waves = exact chip capacity) => spin cannot deadlock.
__global__ __launch_bounds__(1024, 8) void fused_se_kernel(
    const float* __restrict__ x,
    const float* __restrict__ w1, const float* __restrict__ b1,
    const float* __restrict__ w2, const float* __restrict__ b2,
    float* __restrict__ out,
    float* __restrict__ pool_ws, unsigned* __restrict__ flags)
{
    const int g     = blockIdx.x;
    const int slice = g >> 1;
    const int half  = g & 1;
    const int b = slice >> 4, d = slice & 15;
    const int tid = threadIdx.x, wave = tid >> 6, lane = tid & 63;
    const int cbase = half * 32;
    const int c0 = cbase + wave * 2;          // first of this wave's 2 channels

    __shared__ float pooled_all[CC];
    __shared__ float hbuf[HID];
    __shared__ float gate_s[32];

    const size_t base4 = ((size_t)(b * CC) * DD + d) * (HW / 4);

    uint2 rv[18];                             // 2 ch x 9 f4, bf16-packed

    // ---- Phase 1: read + pool + pack into registers ----
    #pragma unroll
    for (int ch = 0; ch < 2; ++ch) {
        const f4* p = (const f4*)x + base4 + (size_t)(c0 + ch) * CH4 + lane;
        float s = 0.f;
        #pragma unroll
        for (int j = 0; j < 9; ++j) {
            f4 v = p[j * 64];
            s += (v.x + v.y) + (v.z + v.w);
            rv[ch * 9 + j] = pack_bf16x4(v);
        }
        #pragma unroll
        for (int m = 32; m; m >>= 1) s += __shfl_xor(s, m, 64);
        if (lane == 0) pooled_all[c0 + ch] = s * (1.0f / HW);
    }
    __syncthreads();

    // ---- Handshake: publish our 32 pools, wait for sibling's 32 ----
    if (tid < 32) {
        __hip_atomic_store(&pool_ws[slice * CC + cbase + tid],
                           pooled_all[cbase + tid],
                           __ATOMIC_RELAXED, __HIP_MEMORY_SCOPE_AGENT);
        // per-publisher release: partner's acquire sees this lane's store
        __hip_atomic_fetch_add(&flags[slice], 1u,
                               __ATOMIC_RELEASE, __HIP_MEMORY_SCOPE_AGENT);
    }
    if (tid == 0) {
        while (__hip_atomic_load(&flags[slice], __ATOMIC_ACQUIRE,
                                 __HIP_MEMORY_SCOPE_AGENT) < 64u)
            __builtin_amdgcn_s_sleep(2);
    }
    __syncthreads();
    if (tid < CC)   // atomic loads: coherent path, safe cross-XCD
        pooled_all[tid] = __hip_atomic_load(&pool_ws[slice * CC + tid],
                                            __ATOMIC_RELAXED,
                                            __HIP_MEMORY_SCOPE_AGENT);
    __syncthreads();

    // ---- MLP: wave w computes hidden[w] via shuffle-reduce ----
    {
        float v = w1[wave * CC + lane] * pooled_all[lane];
        #pragma unroll
        for (int m = 32; m; m >>= 1) v += __shfl_xor(v, m, 64);
        if (lane == 0) {
            float acc = v + b1[wave];
            hbuf[wave] = acc >= 0.f ? acc : NEG_SLOPE * acc;
        }
    }
    __syncthreads();
    if (tid < 32) {
        const int c = cbase + tid;
        float acc = b2[c];
        #pragma unroll
        for (int o = 0; o < HID; ++o) acc += w2[c * HID + o] * hbuf[o];
        gate_s[tid] = 1.0f / (1.0f + expf(-acc));
    }
    __syncthreads();

    // ---- Phase 3: unpack, multiply, NT store ----
    #pragma unroll
    for (int ch = 0; ch < 2; ++ch) {
        const float gv = gate_s[wave * 2 + ch];
        f4* q = (f4*)out + base4 + (size_t)(c0 + ch) * CH4 + lane;
        #pragma unroll
        for (int j = 0; j < 9; ++j)
            __builtin_nontemporal_store(unpack_mul(rv[ch * 9 + j], gv), q + j * 64);
    }
}

extern "C" void kernel_launch(void* const* d_in, const int* in_sizes, int n_in,
                              void* d_out, int out_size, void* d_ws, size_t ws_size,
                              hipStream_t stream) {
    const float* x  = (const float*)d_in[0];
    const float* w1 = (const float*)d_in[1];
    const float* b1 = (const float*)d_in[2];
    const float* w2 = (const float*)d_in[3];
    const float* b2 = (const float*)d_in[4];
    float* out = (float*)d_out;

    unsigned* flags = (unsigned*)d_ws;                    // 256 counters
    float* pool_ws  = (float*)((char*)d_ws + 1024);       // 256*64 floats

    zero_flags_kernel<<<1, 256, 0, stream>>>(flags);
    fused_se_kernel<<<NBLK, 1024, 0, stream>>>(x, w1, b1, w2, b2, out,
                                               pool_ws, flags);
}

// Round 9
// 55.706 us; speedup vs baseline: 1.3227x; 1.3227x over previous
//
#include <hip/hip_runtime.h>

#define BB 16
#define CC 64
#define DD 16
#define HW 2304     // 48*48
#define HID 16
#define NEG_SLOPE 0.01f
#define CH4 9216    // float4 stride between channels at fixed (b,d)

using f4 = __attribute__((ext_vector_type(4))) float;

// Pack 4 fp32 -> 4 bf16 (two dwords).
__device__ __forceinline__ uint2 pack_bf16x4(f4 v) {
    uint2 r;
    asm("v_cvt_pk_bf16_f32 %0, %1, %2" : "=v"(r.x) : "v"(v.x), "v"(v.y));
    asm("v_cvt_pk_bf16_f32 %0, %1, %2" : "=v"(r.y) : "v"(v.z), "v"(v.w));
    return r;
}

__device__ __forceinline__ f4 unpack_mul(uint2 p, float g) {
    f4 v;
    v.x = __uint_as_float(p.x << 16) * g;
    v.y = __uint_as_float(p.x & 0xffff0000u) * g;
    v.z = __uint_as_float(p.y << 16) * g;
    v.w = __uint_as_float(p.y & 0xffff0000u) * g;
    return v;
}

__device__ __forceinline__ f4 gmul(f4 v, float g) {
    v.x *= g; v.y *= g; v.z *= g; v.w *= g;
    return v;
}

// Per-channel storage split of the 9 float4 slots:
//   slots [0, RC)            -> registers (bf16-packed)   Σ = 18
//   slots [RC, RC+LC)        -> LDS       (bf16-packed)   Σ = 9
//   slots [RC+LC, 9)         -> re-read from global       Σ = 9
__device__ constexpr int RC[4]    = {5, 5, 4, 4};
__device__ constexpr int LC[4]    = {2, 2, 3, 2};
__device__ constexpr int RBASE[4] = {0, 5, 10, 14};
__device__ constexpr int LBASE[4] = {0, 2, 4, 7};

// One block per (b,d) slice (gate stays block-local: NO inter-block coupling,
// R8's handshake regressed 53.5->73.7 us). LDS stage shrunk to 9 slots
// (73.7 KB) so TWO independent slice-blocks co-reside per CU -> 32 waves/CU
// for latency hiding + straggler smoothing. 18 reg slots proven spill-free
// under the 64-VGPR cap in R8 (WRITE_SIZE stayed 148 MB).
__global__ __launch_bounds__(1024, 8) void fused_se_kernel(
    const float* __restrict__ x,
    const float* __restrict__ w1, const float* __restrict__ b1,
    const float* __restrict__ w2, const float* __restrict__ b2,
    float* __restrict__ out)
{
    const int bd   = blockIdx.x;
    const int b    = bd >> 4;
    const int d    = bd & 15;
    const int tid  = threadIdx.x;
    const int wave = tid >> 6;
    const int lane = tid & 63;

    __shared__ uint2 stage[9][1024];       // 73,728 B
    __shared__ float pooled[CC];
    __shared__ float hbuf[HID];
    __shared__ float gate_s[CC];

    const size_t base4 = ((size_t)(b * CC) * DD + d) * (HW / 4);
    const f4* xb = (const f4*)x + base4 + lane;

    uint2 rv[18];

    // ---- Phase 1: read + pool + pack on-chip (27/36 slots retained) ----
    #pragma unroll
    for (int i = 0; i < 4; ++i) {
        const f4* p = xb + (size_t)(wave * 4 + i) * CH4;
        float s = 0.f;
        #pragma unroll
        for (int j = 0; j < 9; ++j) {
            f4 v = p[j * 64];
            s += (v.x + v.y) + (v.z + v.w);
            if (j < RC[i])              rv[RBASE[i] + j] = pack_bf16x4(v);
            else if (j < RC[i] + LC[i]) stage[LBASE[i] + j - RC[i]][tid] = pack_bf16x4(v);
            // else: re-read in phase 3
        }
        #pragma unroll
        for (int m = 32; m; m >>= 1) s += __shfl_xor(s, m, 64);
        if (lane == 0) pooled[wave * 4 + i] = s * (1.0f / HW);
    }
    __syncthreads();

    // ---- Phase 2: tiny MLP (wave-parallel layer 1) ----
    {
        float v = w1[wave * CC + lane] * pooled[lane];
        #pragma unroll
        for (int m = 32; m; m >>= 1) v += __shfl_xor(v, m, 64);
        if (lane == 0) {
            float acc = v + b1[wave];
            hbuf[wave] = acc >= 0.f ? acc : NEG_SLOPE * acc;
        }
    }
    __syncthreads();
    if (tid < CC) {
        float acc = b2[tid];
        #pragma unroll
        for (int o = 0; o < HID; ++o) acc += w2[tid * HID + o] * hbuf[o];
        gate_s[tid] = 1.0f / (1.0f + expf(-acc));
    }
    __syncthreads();

    // ---- Phase 3: per channel: issue re-reads early, then store reg/LDS
    //      slots (hides re-read latency), then store re-read slots ----
    f4* ob = (f4*)out + base4 + lane;
    #pragma unroll
    for (int i = 0; i < 4; ++i) {
        const float gv = gate_s[wave * 4 + i];
        const f4* p = xb + (size_t)(wave * 4 + i) * CH4;
        f4*       q = ob + (size_t)(wave * 4 + i) * CH4;

        f4 rr[3];
        const int nrr = 9 - RC[i] - LC[i];
        #pragma unroll
        for (int k = 0; k < 3; ++k)
            if (k < nrr) rr[k] = p[(RC[i] + LC[i] + k) * 64];

        #pragma unroll
        for (int j = 0; j < 9; ++j) {
            if (j < RC[i])
                __builtin_nontemporal_store(unpack_mul(rv[RBASE[i] + j], gv), q + j * 64);
            else if (j < RC[i] + LC[i])
                __builtin_nontemporal_store(unpack_mul(stage[LBASE[i] + j - RC[i]][tid], gv), q + j * 64);
        }
        #pragma unroll
        for (int k = 0; k < 3; ++k)
            if (k < nrr)
                __builtin_nontemporal_store(gmul(rr[k], gv), q + (RC[i] + LC[i] + k) * 64);
    }
}

extern "C" void kernel_launch(void* const* d_in, const int* in_sizes, int n_in,
                              void* d_out, int out_size, void* d_ws, size_t ws_size,
                              hipStream_t stream) {
    const float* x  = (const float*)d_in[0];
    const float* w1 = (const float*)d_in[1];
    const float* b1 = (const float*)d_in[2];
    const float* w2 = (const float*)d_in[3];
    const float* b2 = (const float*)d_in[4];
    float* out = (float*)d_out;

    fused_se_kernel<<<BB * DD, 1024, 0, stream>>>(x, w1, b1, w2, b2, out);
}